// Round 3
// baseline (221.196 us; speedup 1.0000x reference)
//
#include <hip/hip_runtime.h>
#include <hip/hip_bf16.h>
#include <stdint.h>

#define B_   8
#define L_   2048
#define D_   768
#define H_   16
#define DH   48
#define E_   300
#define EP   320   // E padded to 320 (zeros -> relu(0)=0, exact no-op)
#define KP   64    // dh padded to 64 for K of MFMA1
#define ACH  4     // phaseA L-chunks
#define N1T  (128 * DH * EP)   // one partial-out1 plane

typedef __bf16 bf16;
typedef __bf16 bf16x8 __attribute__((ext_vector_type(8)));
typedef __bf16 bf16x4 __attribute__((ext_vector_type(4)));
typedef float  f32x4  __attribute__((ext_vector_type(4)));

typedef const __attribute__((address_space(1))) uint32_t guint;
typedef __attribute__((address_space(3))) uint32_t luint;

__device__ __forceinline__ f32x4 mfma16(bf16x8 a, bf16x8 b, f32x4 c) {
  return __builtin_amdgcn_mfma_f32_16x16x32_bf16(a, b, c, 0, 0, 0);
}

// ---- prep: cast q,k fp32 -> bf16 ----
__global__ __launch_bounds__(256) void k_cast(const float* __restrict__ q,
                                              const float* __restrict__ k,
                                              bf16* __restrict__ qc,
                                              bf16* __restrict__ kc) {
  const float* src = blockIdx.y ? k : q;
  bf16* dst = blockIdx.y ? kc : qc;
  const int n8 = B_ * L_ * D_ / 8;
  for (int i = blockIdx.x * 256 + threadIdx.x; i < n8; i += gridDim.x * 256) {
    float4 f0 = *(const float4*)(src + (size_t)i * 8);
    float4 f1 = *(const float4*)(src + (size_t)i * 8 + 4);
    bf16x8 v;
    v[0] = (bf16)f0.x; v[1] = (bf16)f0.y; v[2] = (bf16)f0.z; v[3] = (bf16)f0.w;
    v[4] = (bf16)f1.x; v[5] = (bf16)f1.y; v[6] = (bf16)f1.z; v[7] = (bf16)f1.w;
    *(bf16x8*)(dst + (size_t)i * 8) = v;
  }
}

// ---- prep: W (k-major) -> WT bf16 (n-major, K contiguous), both weights ----
__global__ __launch_bounds__(256) void k_wt(const float* __restrict__ Wq,
                                            const float* __restrict__ Wv,
                                            bf16* __restrict__ WqT,
                                            bf16* __restrict__ WvT) {
  int idx = blockIdx.x * 256 + threadIdx.x;   // 768*768
  int n = idx / D_, k = idx % D_;
  const float* W = blockIdx.y ? Wv : Wq;
  bf16* WT = blockIdx.y ? WvT : WqT;
  WT[n * D_ + k] = (bf16)W[k * D_ + n];
}

// ---- prep: memory (E,H,dh) -> MP [h][320][64] bf16, zero-padded ----
__global__ __launch_bounds__(256) void k_mem(const float* __restrict__ M,
                                             bf16* __restrict__ MP) {
  int idx = blockIdx.x * 256 + threadIdx.x;   // 16*320*64
  int h = idx / (EP * KP);
  int r = idx % (EP * KP);
  int e = r / KP, d = r % KP;
  float v = (e < E_ && d < DH) ? M[(e * H_ + h) * DH + d] : 0.f;
  MP[idx] = (bf16)v;
}

// ---- projection GEMM: C[16384x768] = A(bf16) @ W + bias, BM=128 BN=256 ----
__global__ __launch_bounds__(256) void k_gemm(
    const bf16* __restrict__ A0, const bf16* __restrict__ A1,
    const bf16* __restrict__ WT0, const bf16* __restrict__ WT1,
    const float* __restrict__ b0, const float* __restrict__ b1,
    bf16* __restrict__ outQ, bf16* __restrict__ outVT) {
  __shared__ bf16 As[128 * 32];   //  8 KB linear
  __shared__ bf16 Bs[256 * 32];   // 16 KB linear
  const int tid = threadIdx.x, lane = tid & 63, w = tid >> 6;
  const int wr = w >> 1, wc = w & 1;
  const int lr = lane & 15, lq = lane >> 4;
  // XCD-chunked swizzle: 384 = 8 XCDs x 48; same m-panel's 3 n-blocks run
  // consecutively on one XCD -> A panel (196KB x 16 panels = 3.1MB) L2-hits.
  const int bid = blockIdx.x;
  const int j = (bid & 7) * 48 + (bid >> 3);
  const int n0 = (j % 3) * 256, m0 = (j / 3) * 128;
  const int mode = blockIdx.y;
  const bf16* A = mode ? A1 : A0;
  const bf16* WT = mode ? WT1 : WT0;
  const float* bias = mode ? b1 : b0;

  f32x4 acc[4][8] = {};

  for (int k0 = 0; k0 < D_; k0 += 32) {
    __syncthreads();
#pragma unroll
    for (int t = 0; t < 2; ++t) {
      int idx = tid + t * 256;
      const bf16* src = A + (size_t)(m0 + (idx >> 2)) * D_ + k0 + (idx & 3) * 8;
      __builtin_amdgcn_global_load_lds((guint*)src, (luint*)&As[t * 2048 + w * 512], 16, 0, 0);
    }
#pragma unroll
    for (int t = 0; t < 4; ++t) {
      int idx = tid + t * 256;
      const bf16* src = WT + (size_t)(n0 + (idx >> 2)) * D_ + k0 + (idx & 3) * 8;
      __builtin_amdgcn_global_load_lds((guint*)src, (luint*)&Bs[t * 2048 + w * 512], 16, 0, 0);
    }
    __syncthreads();
    bf16x8 af[4], bfr[8];
#pragma unroll
    for (int mi = 0; mi < 4; ++mi)
      af[mi] = *(const bf16x8*)&As[(wr * 64 + mi * 16 + lr) * 32 + lq * 8];
#pragma unroll
    for (int ni = 0; ni < 8; ++ni)
      bfr[ni] = *(const bf16x8*)&Bs[(wc * 128 + ni * 16 + lr) * 32 + lq * 8];
#pragma unroll
    for (int mi = 0; mi < 4; ++mi)
#pragma unroll
      for (int ni = 0; ni < 8; ++ni)
        acc[mi][ni] = mfma16(af[mi], bfr[ni], acc[mi][ni]);
  }

  float bs[8];
#pragma unroll
  for (int ni = 0; ni < 8; ++ni) bs[ni] = bias[n0 + wc * 128 + ni * 16 + lr];

  if (mode == 0) {
#pragma unroll
    for (int mi = 0; mi < 4; ++mi)
#pragma unroll
      for (int ni = 0; ni < 8; ++ni) {
        int m = m0 + wr * 64 + mi * 16 + lq * 4;
        int n = n0 + wc * 128 + ni * 16 + lr;
#pragma unroll
        for (int r = 0; r < 4; ++r)
          outQ[(size_t)(m + r) * D_ + n] = (bf16)(acc[mi][ni][r] + bs[ni]);
      }
  } else {
#pragma unroll
    for (int mi = 0; mi < 4; ++mi)
#pragma unroll
      for (int ni = 0; ni < 8; ++ni) {
        int mb = m0 + wr * 64 + mi * 16 + lq * 4;
        int n = n0 + wc * 128 + ni * 16 + lr;
        int bhd = (mb >> 11) * H_ + n / DH;
        int d = n % DH;
        int l = mb & (L_ - 1);
        bf16x4 v;
#pragma unroll
        for (int r = 0; r < 4; ++r) v[r] = (bf16)(acc[mi][ni][r] + bs[ni]);
        *(bf16x4*)&outVT[((size_t)bhd * DH + d) * L_ + l] = v;
      }
  }
}

// ---- phase A: partial out1 = relu(mem @ Q^T) @ V over an L/4 chunk ----
__global__ __launch_bounds__(256) void k_phaseA(
    const bf16* __restrict__ Qb, const bf16* __restrict__ VT,
    const bf16* __restrict__ MP, float* __restrict__ O1P) {
  __shared__ bf16 Qs[2][32 * 88];
  __shared__ bf16 Vs[2][48 * 40];
  __shared__ bf16 Ss[EP * 40];
  const int tid = threadIdx.x, lane = tid & 63, w = tid >> 6;
  const int lr = lane & 15, lq = lane >> 4;
  const int bh = blockIdx.y, b = bh >> 4, h = bh & 15;
  const int lbase = blockIdx.x * (L_ / ACH);

  bf16x8 mf[5][2];
#pragma unroll
  for (int mi = 0; mi < 5; ++mi)
#pragma unroll
    for (int kh = 0; kh < 2; ++kh)
      mf[mi][kh] = *(const bf16x8*)&MP[(size_t)(h * EP + w * 80 + mi * 16 + lr) * KP + kh * 32 + lq * 8];

  if (tid < 128) {
    int buf = tid >> 6, t = tid & 63;
    uint4 z = {0, 0, 0, 0};
    *(uint4*)&Qs[buf][(t >> 1) * 88 + 48 + (t & 1) * 8] = z;
  }

  auto loadQ = [&](int idx, int l0) {
    return *(const bf16x8*)&Qb[(size_t)(b * L_ + l0 + idx / 6) * D_ + h * DH + (idx % 6) * 8];
  };
  auto loadV = [&](int j, int l0) {
    return *(const bf16x8*)&VT[((size_t)bh * DH + (j >> 2)) * L_ + l0 + (j & 3) * 8];
  };

  bf16x8 rA, rB;
  {
    int l0 = lbase;
    rA = (tid < 192) ? loadQ(tid, l0) : loadV(tid - 192, l0);
    if (tid < 128) rB = loadV(tid + 64, l0);
  }

  f32x4 acc[5][3] = {};

  for (int it = 0; it < L_ / ACH / 32; ++it) {
    const int cur = it & 1;
    if (tid < 192) *(bf16x8*)&Qs[cur][(tid / 6) * 88 + (tid % 6) * 8] = rA;
    else           *(bf16x8*)&Vs[cur][((tid - 192) >> 2) * 40 + ((tid - 192) & 3) * 8] = rA;
    if (tid < 128) *(bf16x8*)&Vs[cur][((tid + 64) >> 2) * 40 + ((tid + 64) & 3) * 8] = rB;
    __syncthreads();
    if (it + 1 < L_ / ACH / 32) {
      int l0 = lbase + (it + 1) * 32;
      rA = (tid < 192) ? loadQ(tid, l0) : loadV(tid - 192, l0);
      if (tid < 128) rB = loadV(tid + 64, l0);
    }
    bf16x8 qf[2][2];
#pragma unroll
    for (int ni = 0; ni < 2; ++ni)
#pragma unroll
      for (int kh = 0; kh < 2; ++kh)
        qf[ni][kh] = *(const bf16x8*)&Qs[cur][(ni * 16 + lr) * 88 + kh * 32 + lq * 8];
#pragma unroll
    for (int mi = 0; mi < 5; ++mi)
#pragma unroll
      for (int ni = 0; ni < 2; ++ni) {
        f32x4 s = {0.f, 0.f, 0.f, 0.f};
        s = mfma16(mf[mi][0], qf[ni][0], s);
        s = mfma16(mf[mi][1], qf[ni][1], s);
#pragma unroll
        for (int r = 0; r < 4; ++r)
          Ss[(w * 80 + mi * 16 + lq * 4 + r) * 40 + ni * 16 + lr] =
              (bf16)(s[r] > 0.f ? s[r] : 0.f);
      }
    bf16x8 sf[5], vf[3];
#pragma unroll
    for (int mi = 0; mi < 5; ++mi)
      sf[mi] = *(const bf16x8*)&Ss[(w * 80 + mi * 16 + lr) * 40 + lq * 8];
#pragma unroll
    for (int ni = 0; ni < 3; ++ni)
      vf[ni] = *(const bf16x8*)&Vs[cur][(ni * 16 + lr) * 40 + lq * 8];
#pragma unroll
    for (int mi = 0; mi < 5; ++mi)
#pragma unroll
      for (int ni = 0; ni < 3; ++ni)
        acc[mi][ni] = mfma16(sf[mi], vf[ni], acc[mi][ni]);
  }
  float* dst = O1P + (size_t)(blockIdx.x * 128 + bh) * DH * EP;
#pragma unroll
  for (int mi = 0; mi < 5; ++mi)
#pragma unroll
    for (int ni = 0; ni < 3; ++ni) {
      int e = w * 80 + mi * 16 + lq * 4;
      int d = ni * 16 + lr;
#pragma unroll
      for (int r = 0; r < 4; ++r)
        dst[(size_t)d * EP + e + r] = acc[mi][ni][r];
    }
}

// ---- reduce partials -> O1T bf16 [bh][d][320] ----
__global__ __launch_bounds__(256) void k_red(const float* __restrict__ O1P,
                                             bf16* __restrict__ O1T) {
  int idx = blockIdx.x * 256 + threadIdx.x;
  if (idx >= N1T) return;
  float s = O1P[idx];
#pragma unroll
  for (int c = 1; c < ACH; ++c) s += O1P[(size_t)c * N1T + idx];
  O1T[idx] = (bf16)s;
}

// ---- phase B: x = relu(Q @ mem^T) @ out1, e-chunked (5 x 64) ----
__global__ __launch_bounds__(256, 4) void k_phaseB(
    const bf16* __restrict__ Qb, const bf16* __restrict__ MP,
    const bf16* __restrict__ O1T, bf16* __restrict__ X) {
  __shared__ bf16 Qs[64 * 88];
  __shared__ bf16 STs[64 * 76];
  __shared__ bf16 O1s[2][48 * 76];
  const int tid = threadIdx.x, lane = tid & 63, w = tid >> 6;
  const int lr = lane & 15, lq = lane >> 4;
  const int bh = blockIdx.y, b = bh >> 4, h = bh & 15;
  const int l0 = blockIdx.x * 64;

  bf16x8 mfB[5][2];
#pragma unroll
  for (int c = 0; c < 5; ++c)
#pragma unroll
    for (int kh = 0; kh < 2; ++kh)
      mfB[c][kh] = *(const bf16x8*)&MP[(size_t)(h * EP + c * 64 + w * 16 + lr) * KP + kh * 32 + lq * 8];

  for (int idx = tid; idx < 512; idx += 256) {
    if (idx < 384) {
      int row = idx / 6, c = idx % 6;
      *(bf16x8*)&Qs[row * 88 + c * 8] =
          *(const bf16x8*)&Qb[(size_t)(b * L_ + l0 + row) * D_ + h * DH + c * 8];
    } else {
      int j = idx - 384;
      uint4 z = {0, 0, 0, 0};
      *(uint4*)&Qs[(j >> 1) * 88 + 48 + (j & 1) * 8] = z;
    }
  }
  for (int idx = tid; idx < 384; idx += 256)
    *(bf16x8*)&O1s[0][(idx >> 3) * 76 + (idx & 7) * 8] =
        *(const bf16x8*)&O1T[((size_t)bh * DH + (idx >> 3)) * EP + (idx & 7) * 8];
  __syncthreads();

  f32x4 acc[3] = {};
#pragma unroll
  for (int c = 0; c < 5; ++c) {
    bf16x8 r0, r1;
    if (c < 4) {
      r0 = *(const bf16x8*)&O1T[((size_t)bh * DH + (tid >> 3)) * EP + (c + 1) * 64 + (tid & 7) * 8];
      if (tid < 128) {
        int i2 = tid + 256;
        r1 = *(const bf16x8*)&O1T[((size_t)bh * DH + (i2 >> 3)) * EP + (c + 1) * 64 + (i2 & 7) * 8];
      }
    }
#pragma unroll
    for (int mi = 0; mi < 4; ++mi) {
      bf16x8 qa0 = *(const bf16x8*)&Qs[(mi * 16 + lr) * 88 + lq * 8];
      bf16x8 qa1 = *(const bf16x8*)&Qs[(mi * 16 + lr) * 88 + 32 + lq * 8];
      f32x4 s = {0.f, 0.f, 0.f, 0.f};
      s = mfma16(qa0, mfB[c][0], s);
      s = mfma16(qa1, mfB[c][1], s);
#pragma unroll
      for (int r = 0; r < 4; ++r)
        STs[(mi * 16 + lq * 4 + r) * 76 + w * 16 + lr] =
            (bf16)(s[r] > 0.f ? s[r] : 0.f);
    }
    __syncthreads();
#pragma unroll
    for (int ks = 0; ks < 2; ++ks) {
      bf16x8 sf = *(const bf16x8*)&STs[(w * 16 + lr) * 76 + ks * 32 + lq * 8];
#pragma unroll
      for (int ni = 0; ni < 3; ++ni) {
        bf16x8 of = *(const bf16x8*)&O1s[c & 1][(ni * 16 + lr) * 76 + ks * 32 + lq * 8];
        acc[ni] = mfma16(sf, of, acc[ni]);
      }
    }
    if (c < 4) {
      *(bf16x8*)&O1s[(c + 1) & 1][(tid >> 3) * 76 + (tid & 7) * 8] = r0;
      if (tid < 128) {
        int i2 = tid + 256;
        *(bf16x8*)&O1s[(c + 1) & 1][(i2 >> 3) * 76 + (i2 & 7) * 8] = r1;
      }
    }
    __syncthreads();
  }
#pragma unroll
  for (int ni = 0; ni < 3; ++ni)
#pragma unroll
    for (int r = 0; r < 4; ++r)
      X[(size_t)(b * L_ + l0 + w * 16 + lq * 4 + r) * D_ + h * DH + ni * 16 + lr] =
          (bf16)acc[ni][r];
}

// ---- LayerNorm over D=768, eps=1e-3: 1 wave per row, vectorized ----
__global__ __launch_bounds__(256) void k_ln(
    const bf16* __restrict__ X, const float* __restrict__ gamma,
    const float* __restrict__ beta, float* __restrict__ out) {
  const int lane = threadIdx.x & 63;
  const int row = blockIdx.x * 4 + (threadIdx.x >> 6);
  const bf16* x = X + (size_t)row * D_;
  float v[12];
#pragma unroll
  for (int c = 0; c < 3; ++c) {
    bf16x4 ch = *(const bf16x4*)(x + lane * 12 + c * 4);
#pragma unroll
    for (int j = 0; j < 4; ++j) v[c * 4 + j] = (float)ch[j];
  }
  float s = 0.f, q = 0.f;
#pragma unroll
  for (int j = 0; j < 12; ++j) { s += v[j]; q += v[j] * v[j]; }
#pragma unroll
  for (int off = 32; off > 0; off >>= 1) {
    s += __shfl_xor(s, off);
    q += __shfl_xor(q, off);
  }
  float mean = s * (1.f / 768.f);
  float var = q * (1.f / 768.f) - mean * mean;
  float inv = rsqrtf(var + 1e-3f);
  float* o = out + (size_t)row * D_;
#pragma unroll
  for (int c = 0; c < 3; ++c) {
    float4 g = *(const float4*)(gamma + lane * 12 + c * 4);
    float4 bt = *(const float4*)(beta + lane * 12 + c * 4);
    float4 r;
    r.x = (v[c * 4 + 0] - mean) * inv * g.x + bt.x;
    r.y = (v[c * 4 + 1] - mean) * inv * g.y + bt.y;
    r.z = (v[c * 4 + 2] - mean) * inv * g.z + bt.z;
    r.w = (v[c * 4 + 3] - mean) * inv * g.w + bt.w;
    *(float4*)(o + lane * 12 + c * 4) = r;
  }
}

extern "C" void kernel_launch(void* const* d_in, const int* in_sizes, int n_in,
                              void* d_out, int out_size, void* d_ws, size_t ws_size,
                              hipStream_t stream) {
  (void)in_sizes; (void)n_in; (void)out_size; (void)ws_size;
  const float* q_in = (const float*)d_in[0];
  const float* k_in = (const float*)d_in[1];
  const float* Wq   = (const float*)d_in[3];
  const float* bq   = (const float*)d_in[4];
  const float* Wv   = (const float*)d_in[5];
  const float* bv   = (const float*)d_in[6];
  const float* mem  = (const float*)d_in[7];
  const float* gam  = (const float*)d_in[8];
  const float* bet  = (const float*)d_in[9];
  float* out = (float*)d_out;

  char* ws = (char*)d_ws;
  size_t off = 0;
  auto alloc = [&](size_t bytes) {
    char* p = ws + off;
    off += (bytes + 255) & ~(size_t)255;
    return p;
  };
  bf16*  WqT = (bf16*)alloc((size_t)D_ * D_ * 2);
  bf16*  WvT = (bf16*)alloc((size_t)D_ * D_ * 2);
  bf16*  MP  = (bf16*)alloc((size_t)H_ * EP * KP * 2);
  bf16*  Qb  = (bf16*)alloc((size_t)B_ * L_ * D_ * 2);
  bf16*  VT  = (bf16*)alloc((size_t)B_ * H_ * DH * L_ * 2);
  bf16*  O1T = (bf16*)alloc((size_t)N1T * 2);
  // big region, time-multiplexed: {qc,kc} (cast->gemm) -> O1P (phaseA->red) -> Xb (phaseB->ln)
  const size_t castHalf = ((size_t)B_ * L_ * D_ * 2 + 256) & ~(size_t)255;
  const size_t castBytes = 2 * castHalf;
  const size_t o1pBytes  = (size_t)ACH * N1T * 4;
  char*  big = alloc(castBytes > o1pBytes ? castBytes : o1pBytes);
  bf16*  qc  = (bf16*)big;
  bf16*  kc  = (bf16*)(big + castHalf);
  float* O1P = (float*)big;
  bf16*  Xb  = (bf16*)big;

  k_cast<<<dim3(2048, 2), 256, 0, stream>>>(q_in, k_in, qc, kc);
  k_wt<<<dim3((D_ * D_) / 256, 2), 256, 0, stream>>>(Wq, Wv, WqT, WvT);
  k_mem<<<(H_ * EP * KP) / 256, 256, 0, stream>>>(mem, MP);
  k_gemm<<<dim3(384, 2), 256, 0, stream>>>(qc, kc, WqT, WvT, bq, bv, Qb, VT);
  k_phaseA<<<dim3(ACH, B_ * H_), 256, 0, stream>>>(Qb, VT, MP, O1P);
  k_red<<<(N1T + 255) / 256, 256, 0, stream>>>(O1P, O1T);
  k_phaseB<<<dim3(L_ / 64, B_ * H_), 256, 0, stream>>>(Qb, MP, O1T, Xb);
  k_ln<<<(B_ * L_) / 4, 256, 0, stream>>>(Xb, gam, bet, out);
}

// Round 4
// 175.720 us; speedup vs baseline: 1.2588x; 1.2588x over previous
//
#include <hip/hip_runtime.h>
#include <hip/hip_bf16.h>
#include <stdint.h>

#define B_   8
#define L_   2048
#define D_   768
#define H_   16
#define DH   48
#define E_   300
#define EP   320   // E padded to 320 (zeros -> relu(0)=0, exact no-op)
#define KP   64    // dh padded to 64 for K of MFMA1
#define ACH  4     // phaseA L-chunks
#define N1T  (128 * DH * EP)   // one partial-out1 plane

typedef __bf16 bf16;
typedef __bf16 bf16x8 __attribute__((ext_vector_type(8)));
typedef __bf16 bf16x4 __attribute__((ext_vector_type(4)));
typedef float  f32x4  __attribute__((ext_vector_type(4)));

typedef const __attribute__((address_space(1))) uint32_t guint;
typedef __attribute__((address_space(3))) uint32_t luint;

__device__ __forceinline__ f32x4 mfma16(bf16x8 a, bf16x8 b, f32x4 c) {
  return __builtin_amdgcn_mfma_f32_16x16x32_bf16(a, b, c, 0, 0, 0);
}

// ---- prep: W (k-major) -> WT bf16 (n-major, K contiguous), both weights ----
__global__ __launch_bounds__(256) void k_wt(const float* __restrict__ Wq,
                                            const float* __restrict__ Wv,
                                            bf16* __restrict__ WqT,
                                            bf16* __restrict__ WvT) {
  int idx = blockIdx.x * 256 + threadIdx.x;   // 768*768
  int n = idx / D_, k = idx % D_;
  const float* W = blockIdx.y ? Wv : Wq;
  bf16* WT = blockIdx.y ? WvT : WqT;
  WT[n * D_ + k] = (bf16)W[k * D_ + n];
}

// ---- prep: memory (E,H,dh) -> MP [h][320][64] bf16, zero-padded ----
__global__ __launch_bounds__(256) void k_mem(const float* __restrict__ M,
                                             bf16* __restrict__ MP) {
  int idx = blockIdx.x * 256 + threadIdx.x;   // 16*320*64
  int h = idx / (EP * KP);
  int r = idx % (EP * KP);
  int e = r / KP, d = r % KP;
  float v = (e < E_ && d < DH) ? M[(e * H_ + h) * DH + d] : 0.f;
  MP[idx] = (bf16)v;
}

// ---- projection GEMM: C[16384x768] = cvt(A fp32) @ W + bias ----
// 512 threads, BM=128 BN=256 BK=32, 8 waves as 2(M)x4(N), 64x64 per wave.
// As/Bs XOR slot-swizzled (2-way bank max). A: reg-staged fp32->bf16.
// B: global_load_lds w/ pre-swizzled source col.
__global__ __launch_bounds__(512, 4) void k_gemm(
    const float* __restrict__ A0, const float* __restrict__ A1,
    const bf16* __restrict__ WT0, const bf16* __restrict__ WT1,
    const float* __restrict__ b0, const float* __restrict__ b1,
    bf16* __restrict__ outQ, bf16* __restrict__ outVT) {
  __shared__ bf16 As[128 * 32];   //  8 KB
  __shared__ bf16 Bs[256 * 32];   // 16 KB
  const int tid = threadIdx.x, lane = tid & 63, w = tid >> 6;
  const int wr = w >> 2, wc = w & 3;
  const int lr = lane & 15, lq = lane >> 4;
  // XCD-chunked swizzle: 384 = 8 XCDs x 48; an m-panel's 3 n-blocks run
  // consecutively on one XCD -> fp32 A panel (384KB) stays L2-hot.
  const int bid = blockIdx.x;
  const int j = (bid & 7) * 48 + (bid >> 3);
  const int n0 = (j % 3) * 256, m0 = (j / 3) * 128;
  const int mode = blockIdx.y;
  const float* A = mode ? A1 : A0;
  const bf16* WT = mode ? WT1 : WT0;
  const float* bias = mode ? b1 : b0;

  const int arow = tid >> 2, ac8 = tid & 3;          // A: 128 rows x 4 slots
  const int aslot = ac8 ^ ((arow >> 1) & 3);

  f32x4 acc[4][4] = {};

  for (int k0 = 0; k0 < D_; k0 += 32) {
    __syncthreads();
    // A: fp32 load + convert + swizzled ds_write_b128
    {
      const float* src = A + (size_t)(m0 + arow) * D_ + k0 + ac8 * 8;
      float4 f0 = *(const float4*)src;
      float4 f1 = *(const float4*)(src + 4);
      bf16x8 v;
      v[0] = (bf16)f0.x; v[1] = (bf16)f0.y; v[2] = (bf16)f0.z; v[3] = (bf16)f0.w;
      v[4] = (bf16)f1.x; v[5] = (bf16)f1.y; v[6] = (bf16)f1.z; v[7] = (bf16)f1.w;
      *(bf16x8*)&As[arow * 32 + aslot * 8] = v;
    }
    // B: async global->LDS; linear dest, source col pre-swizzled
#pragma unroll
    for (int t = 0; t < 2; ++t) {
      int idx = tid + t * 512;
      int brow = idx >> 2, bt = idx & 3;
      int bc8 = bt ^ ((brow >> 1) & 3);
      const bf16* src = WT + (size_t)(n0 + brow) * D_ + k0 + bc8 * 8;
      __builtin_amdgcn_global_load_lds((guint*)src,
                                       (luint*)&Bs[(t * 512 + w * 64) * 8], 16, 0, 0);
    }
    __syncthreads();
    bf16x8 af[4], bfr[4];
#pragma unroll
    for (int mi = 0; mi < 4; ++mi) {
      int row = wr * 64 + mi * 16 + lr;
      af[mi] = *(const bf16x8*)&As[row * 32 + (lq ^ ((row >> 1) & 3)) * 8];
    }
#pragma unroll
    for (int ni = 0; ni < 4; ++ni) {
      int row = wc * 64 + ni * 16 + lr;
      bfr[ni] = *(const bf16x8*)&Bs[row * 32 + (lq ^ ((row >> 1) & 3)) * 8];
    }
#pragma unroll
    for (int mi = 0; mi < 4; ++mi)
#pragma unroll
      for (int ni = 0; ni < 4; ++ni)
        acc[mi][ni] = mfma16(af[mi], bfr[ni], acc[mi][ni]);
  }

  float bs[4];
#pragma unroll
  for (int ni = 0; ni < 4; ++ni) bs[ni] = bias[n0 + wc * 64 + ni * 16 + lr];

  if (mode == 0) {
#pragma unroll
    for (int mi = 0; mi < 4; ++mi)
#pragma unroll
      for (int ni = 0; ni < 4; ++ni) {
        int m = m0 + wr * 64 + mi * 16 + lq * 4;
        int n = n0 + wc * 64 + ni * 16 + lr;
#pragma unroll
        for (int r = 0; r < 4; ++r)
          outQ[(size_t)(m + r) * D_ + n] = (bf16)(acc[mi][ni][r] + bs[ni]);
      }
  } else {
#pragma unroll
    for (int mi = 0; mi < 4; ++mi)
#pragma unroll
      for (int ni = 0; ni < 4; ++ni) {
        int mb = m0 + wr * 64 + mi * 16 + lq * 4;
        int n = n0 + wc * 64 + ni * 16 + lr;
        int bhd = (mb >> 11) * H_ + n / DH;
        int d = n % DH;
        int l = mb & (L_ - 1);
        bf16x4 v;
#pragma unroll
        for (int r = 0; r < 4; ++r) v[r] = (bf16)(acc[mi][ni][r] + bs[ni]);
        *(bf16x4*)&outVT[((size_t)bhd * DH + d) * L_ + l] = v;
      }
  }
}

// ---- phase A: partial out1 = relu(mem @ Q^T) @ V over an L/4 chunk ----
__global__ __launch_bounds__(256) void k_phaseA(
    const bf16* __restrict__ Qb, const bf16* __restrict__ VT,
    const bf16* __restrict__ MP, float* __restrict__ O1P) {
  __shared__ bf16 Qs[2][32 * 88];
  __shared__ bf16 Vs[2][48 * 40];
  __shared__ bf16 Ss[EP * 40];
  const int tid = threadIdx.x, lane = tid & 63, w = tid >> 6;
  const int lr = lane & 15, lq = lane >> 4;
  const int bh = blockIdx.y, b = bh >> 4, h = bh & 15;
  const int lbase = blockIdx.x * (L_ / ACH);

  bf16x8 mf[5][2];
#pragma unroll
  for (int mi = 0; mi < 5; ++mi)
#pragma unroll
    for (int kh = 0; kh < 2; ++kh)
      mf[mi][kh] = *(const bf16x8*)&MP[(size_t)(h * EP + w * 80 + mi * 16 + lr) * KP + kh * 32 + lq * 8];

  if (tid < 128) {
    int buf = tid >> 6, t = tid & 63;
    uint4 z = {0, 0, 0, 0};
    *(uint4*)&Qs[buf][(t >> 1) * 88 + 48 + (t & 1) * 8] = z;
  }

  auto loadQ = [&](int idx, int l0) {
    return *(const bf16x8*)&Qb[(size_t)(b * L_ + l0 + idx / 6) * D_ + h * DH + (idx % 6) * 8];
  };
  auto loadV = [&](int j, int l0) {
    return *(const bf16x8*)&VT[((size_t)bh * DH + (j >> 2)) * L_ + l0 + (j & 3) * 8];
  };

  bf16x8 rA, rB;
  {
    int l0 = lbase;
    rA = (tid < 192) ? loadQ(tid, l0) : loadV(tid - 192, l0);
    if (tid < 128) rB = loadV(tid + 64, l0);
  }

  f32x4 acc[5][3] = {};

  for (int it = 0; it < L_ / ACH / 32; ++it) {
    const int cur = it & 1;
    if (tid < 192) *(bf16x8*)&Qs[cur][(tid / 6) * 88 + (tid % 6) * 8] = rA;
    else           *(bf16x8*)&Vs[cur][((tid - 192) >> 2) * 40 + ((tid - 192) & 3) * 8] = rA;
    if (tid < 128) *(bf16x8*)&Vs[cur][((tid + 64) >> 2) * 40 + ((tid + 64) & 3) * 8] = rB;
    __syncthreads();
    if (it + 1 < L_ / ACH / 32) {
      int l0 = lbase + (it + 1) * 32;
      rA = (tid < 192) ? loadQ(tid, l0) : loadV(tid - 192, l0);
      if (tid < 128) rB = loadV(tid + 64, l0);
    }
    bf16x8 qf[2][2];
#pragma unroll
    for (int ni = 0; ni < 2; ++ni)
#pragma unroll
      for (int kh = 0; kh < 2; ++kh)
        qf[ni][kh] = *(const bf16x8*)&Qs[cur][(ni * 16 + lr) * 88 + kh * 32 + lq * 8];
#pragma unroll
    for (int mi = 0; mi < 5; ++mi)
#pragma unroll
      for (int ni = 0; ni < 2; ++ni) {
        f32x4 s = {0.f, 0.f, 0.f, 0.f};
        s = mfma16(mf[mi][0], qf[ni][0], s);
        s = mfma16(mf[mi][1], qf[ni][1], s);
#pragma unroll
        for (int r = 0; r < 4; ++r)
          Ss[(w * 80 + mi * 16 + lq * 4 + r) * 40 + ni * 16 + lr] =
              (bf16)(s[r] > 0.f ? s[r] : 0.f);
      }
    bf16x8 sf[5], vf[3];
#pragma unroll
    for (int mi = 0; mi < 5; ++mi)
      sf[mi] = *(const bf16x8*)&Ss[(w * 80 + mi * 16 + lr) * 40 + lq * 8];
#pragma unroll
    for (int ni = 0; ni < 3; ++ni)
      vf[ni] = *(const bf16x8*)&Vs[cur][(ni * 16 + lr) * 40 + lq * 8];
#pragma unroll
    for (int mi = 0; mi < 5; ++mi)
#pragma unroll
      for (int ni = 0; ni < 3; ++ni)
        acc[mi][ni] = mfma16(sf[mi], vf[ni], acc[mi][ni]);
  }
  float* dst = O1P + (size_t)(blockIdx.x * 128 + bh) * DH * EP;
#pragma unroll
  for (int mi = 0; mi < 5; ++mi)
#pragma unroll
    for (int ni = 0; ni < 3; ++ni) {
      int e = w * 80 + mi * 16 + lq * 4;
      int d = ni * 16 + lr;
#pragma unroll
      for (int r = 0; r < 4; ++r)
        dst[(size_t)d * EP + e + r] = acc[mi][ni][r];
    }
}

// ---- reduce partials -> O1T bf16 [bh][d][320] ----
__global__ __launch_bounds__(256) void k_red(const float* __restrict__ O1P,
                                             bf16* __restrict__ O1T) {
  int idx = blockIdx.x * 256 + threadIdx.x;
  if (idx >= N1T) return;
  float s = O1P[idx];
#pragma unroll
  for (int c = 1; c < ACH; ++c) s += O1P[(size_t)c * N1T + idx];
  O1T[idx] = (bf16)s;
}

// ---- phase B: x = relu(Q @ mem^T) @ out1, e-chunked (5 x 64) ----
__global__ __launch_bounds__(256, 4) void k_phaseB(
    const bf16* __restrict__ Qb, const bf16* __restrict__ MP,
    const bf16* __restrict__ O1T, bf16* __restrict__ X) {
  __shared__ bf16 Qs[64 * 88];
  __shared__ bf16 STs[64 * 76];
  __shared__ bf16 O1s[2][48 * 76];
  const int tid = threadIdx.x, lane = tid & 63, w = tid >> 6;
  const int lr = lane & 15, lq = lane >> 4;
  const int bh = blockIdx.y, b = bh >> 4, h = bh & 15;
  const int l0 = blockIdx.x * 64;

  bf16x8 mfB[5][2];
#pragma unroll
  for (int c = 0; c < 5; ++c)
#pragma unroll
    for (int kh = 0; kh < 2; ++kh)
      mfB[c][kh] = *(const bf16x8*)&MP[(size_t)(h * EP + c * 64 + w * 16 + lr) * KP + kh * 32 + lq * 8];

  for (int idx = tid; idx < 512; idx += 256) {
    if (idx < 384) {
      int row = idx / 6, c = idx % 6;
      *(bf16x8*)&Qs[row * 88 + c * 8] =
          *(const bf16x8*)&Qb[(size_t)(b * L_ + l0 + row) * D_ + h * DH + c * 8];
    } else {
      int j = idx - 384;
      uint4 z = {0, 0, 0, 0};
      *(uint4*)&Qs[(j >> 1) * 88 + 48 + (j & 1) * 8] = z;
    }
  }
  for (int idx = tid; idx < 384; idx += 256)
    *(bf16x8*)&O1s[0][(idx >> 3) * 76 + (idx & 7) * 8] =
        *(const bf16x8*)&O1T[((size_t)bh * DH + (idx >> 3)) * EP + (idx & 7) * 8];
  __syncthreads();

  f32x4 acc[3] = {};
#pragma unroll
  for (int c = 0; c < 5; ++c) {
    bf16x8 r0, r1;
    if (c < 4) {
      r0 = *(const bf16x8*)&O1T[((size_t)bh * DH + (tid >> 3)) * EP + (c + 1) * 64 + (tid & 7) * 8];
      if (tid < 128) {
        int i2 = tid + 256;
        r1 = *(const bf16x8*)&O1T[((size_t)bh * DH + (i2 >> 3)) * EP + (c + 1) * 64 + (i2 & 7) * 8];
      }
    }
#pragma unroll
    for (int mi = 0; mi < 4; ++mi) {
      bf16x8 qa0 = *(const bf16x8*)&Qs[(mi * 16 + lr) * 88 + lq * 8];
      bf16x8 qa1 = *(const bf16x8*)&Qs[(mi * 16 + lr) * 88 + 32 + lq * 8];
      f32x4 s = {0.f, 0.f, 0.f, 0.f};
      s = mfma16(qa0, mfB[c][0], s);
      s = mfma16(qa1, mfB[c][1], s);
#pragma unroll
      for (int r = 0; r < 4; ++r)
        STs[(mi * 16 + lq * 4 + r) * 76 + w * 16 + lr] =
            (bf16)(s[r] > 0.f ? s[r] : 0.f);
    }
    __syncthreads();
#pragma unroll
    for (int ks = 0; ks < 2; ++ks) {
      bf16x8 sf = *(const bf16x8*)&STs[(w * 16 + lr) * 76 + ks * 32 + lq * 8];
#pragma unroll
      for (int ni = 0; ni < 3; ++ni) {
        bf16x8 of = *(const bf16x8*)&O1s[c & 1][(ni * 16 + lr) * 76 + ks * 32 + lq * 8];
        acc[ni] = mfma16(sf, of, acc[ni]);
      }
    }
    if (c < 4) {
      *(bf16x8*)&O1s[(c + 1) & 1][(tid >> 3) * 76 + (tid & 7) * 8] = r0;
      if (tid < 128) {
        int i2 = tid + 256;
        *(bf16x8*)&O1s[(c + 1) & 1][(i2 >> 3) * 76 + (i2 & 7) * 8] = r1;
      }
    }
    __syncthreads();
  }
#pragma unroll
  for (int ni = 0; ni < 3; ++ni)
#pragma unroll
    for (int r = 0; r < 4; ++r)
      X[(size_t)(b * L_ + l0 + w * 16 + lq * 4 + r) * D_ + h * DH + ni * 16 + lr] =
          (bf16)acc[ni][r];
}

// ---- LayerNorm over D=768, eps=1e-3: 1 wave per row, vectorized ----
__global__ __launch_bounds__(256) void k_ln(
    const bf16* __restrict__ X, const float* __restrict__ gamma,
    const float* __restrict__ beta, float* __restrict__ out) {
  const int lane = threadIdx.x & 63;
  const int row = blockIdx.x * 4 + (threadIdx.x >> 6);
  const bf16* x = X + (size_t)row * D_;
  float v[12];
#pragma unroll
  for (int c = 0; c < 3; ++c) {
    bf16x4 ch = *(const bf16x4*)(x + lane * 12 + c * 4);
#pragma unroll
    for (int j = 0; j < 4; ++j) v[c * 4 + j] = (float)ch[j];
  }
  float s = 0.f, q = 0.f;
#pragma unroll
  for (int j = 0; j < 12; ++j) { s += v[j]; q += v[j] * v[j]; }
#pragma unroll
  for (int off = 32; off > 0; off >>= 1) {
    s += __shfl_xor(s, off);
    q += __shfl_xor(q, off);
  }
  float mean = s * (1.f / 768.f);
  float var = q * (1.f / 768.f) - mean * mean;
  float inv = rsqrtf(var + 1e-3f);
  float* o = out + (size_t)row * D_;
#pragma unroll
  for (int c = 0; c < 3; ++c) {
    float4 g = *(const float4*)(gamma + lane * 12 + c * 4);
    float4 bt = *(const float4*)(beta + lane * 12 + c * 4);
    float4 r;
    r.x = (v[c * 4 + 0] - mean) * inv * g.x + bt.x;
    r.y = (v[c * 4 + 1] - mean) * inv * g.y + bt.y;
    r.z = (v[c * 4 + 2] - mean) * inv * g.z + bt.z;
    r.w = (v[c * 4 + 3] - mean) * inv * g.w + bt.w;
    *(float4*)(o + lane * 12 + c * 4) = r;
  }
}

extern "C" void kernel_launch(void* const* d_in, const int* in_sizes, int n_in,
                              void* d_out, int out_size, void* d_ws, size_t ws_size,
                              hipStream_t stream) {
  (void)in_sizes; (void)n_in; (void)out_size; (void)ws_size;
  const float* q_in = (const float*)d_in[0];
  const float* k_in = (const float*)d_in[1];
  const float* Wq   = (const float*)d_in[3];
  const float* bq   = (const float*)d_in[4];
  const float* Wv   = (const float*)d_in[5];
  const float* bv   = (const float*)d_in[6];
  const float* mem  = (const float*)d_in[7];
  const float* gam  = (const float*)d_in[8];
  const float* bet  = (const float*)d_in[9];
  float* out = (float*)d_out;

  char* ws = (char*)d_ws;
  size_t off = 0;
  auto alloc = [&](size_t bytes) {
    char* p = ws + off;
    off += (bytes + 255) & ~(size_t)255;
    return p;
  };
  bf16*  WqT = (bf16*)alloc((size_t)D_ * D_ * 2);
  bf16*  WvT = (bf16*)alloc((size_t)D_ * D_ * 2);
  bf16*  MP  = (bf16*)alloc((size_t)H_ * EP * KP * 2);
  bf16*  Qb  = (bf16*)alloc((size_t)B_ * L_ * D_ * 2);
  bf16*  VT  = (bf16*)alloc((size_t)B_ * H_ * DH * L_ * 2);
  bf16*  O1T = (bf16*)alloc((size_t)N1T * 2);
  // big region, time-multiplexed: O1P (phaseA->red) -> Xb (phaseB->ln)
  const size_t o1pBytes = (size_t)ACH * N1T * 4;
  const size_t xbBytes  = (size_t)B_ * L_ * D_ * 2;
  char*  big = alloc(xbBytes > o1pBytes ? xbBytes : o1pBytes);
  float* O1P = (float*)big;
  bf16*  Xb  = (bf16*)big;

  k_wt<<<dim3((D_ * D_) / 256, 2), 256, 0, stream>>>(Wq, Wv, WqT, WvT);
  k_mem<<<(H_ * EP * KP) / 256, 256, 0, stream>>>(mem, MP);
  k_gemm<<<dim3(384, 2), 512, 0, stream>>>(q_in, k_in, WqT, WvT, bq, bv, Qb, VT);
  k_phaseA<<<dim3(ACH, B_ * H_), 256, 0, stream>>>(Qb, VT, MP, O1P);
  k_red<<<(N1T + 255) / 256, 256, 0, stream>>>(O1P, O1T);
  k_phaseB<<<dim3(L_ / 64, B_ * H_), 256, 0, stream>>>(Qb, MP, O1T, Xb);
  k_ln<<<(B_ * L_) / 4, 256, 0, stream>>>(Xb, gam, bet, out);
}